// Round 12
// baseline (490.482 us; speedup 1.0000x reference)
//
#include <hip/hip_runtime.h>
#include <hip/hip_bf16.h>

#define N_NODES 100000
#define N_EDGES 1600000
#define DIM 128
#define SCAN_CHUNK 1024

typedef __attribute__((ext_vector_type(8))) short bf16x8;
typedef __attribute__((ext_vector_type(4))) float f32x4;
typedef __attribute__((ext_vector_type(4))) short bf16x4;

__device__ __forceinline__ float b2f(short s) {
    return __uint_as_float(((unsigned int)(unsigned short)s) << 16);
}

// Merged kernel: blocks [0,2048) do degrank (atomic-issue-bound, idle BW);
// blocks [2048,...) do fp32->bf16 conversions (BW-bound) — they co-schedule.
__global__ __launch_bounds__(256) void degcvt_kernel(const int* __restrict__ dst,
                                                     int* __restrict__ deg,
                                                     int* __restrict__ rank,
                                                     const float* __restrict__ emb,
                                                     const float* __restrict__ w1,
                                                     const float* __restrict__ w2,
                                                     __hip_bfloat16* __restrict__ embb,
                                                     __hip_bfloat16* __restrict__ w1b,
                                                     __hip_bfloat16* __restrict__ w2b) {
    if (blockIdx.x < 2048) {
        // degrank at full residency; 4 slots/thread, slots 0-2 always in-bounds
        const int S = 2048 * 256;
        int tid = blockIdx.x * blockDim.x + threadIdx.x;
        int e3 = tid + 3 * S;
        int d0 = dst[tid];
        int d1 = dst[tid + S];
        int d2 = dst[tid + 2 * S];
        int d3 = (e3 < N_EDGES) ? dst[e3] : -1;
        int r0 = atomicAdd(&deg[d0], 1);
        int r1 = atomicAdd(&deg[d1], 1);
        int r2 = atomicAdd(&deg[d2], 1);
        int r3 = (d3 >= 0) ? atomicAdd(&deg[d3], 1) : 0;
        rank[tid] = r0;
        rank[tid + S] = r1;
        rank[tid + 2 * S] = r2;
        if (e3 < N_EDGES) rank[e3] = r3;
    } else {
        const int n4e = N_NODES * DIM / 4;
        const int n4w = DIM * DIM / 4;
        int i = (blockIdx.x - 2048) * blockDim.x + threadIdx.x;
        const float* in;
        __hip_bfloat16* out;
        int j;
        if (i < n4e) { in = emb; out = embb; j = i; }
        else if (i < n4e + n4w) { in = w1; out = w1b; j = i - n4e; }
        else if (i < n4e + 2 * n4w) { in = w2; out = w2b; j = i - n4e - n4w; }
        else return;
        f32x4 v = ((const f32x4*)in)[j];
        bf16x4 o;
        o.x = (short)__bfloat16_as_ushort(__float2bfloat16(v.x));
        o.y = (short)__bfloat16_as_ushort(__float2bfloat16(v.y));
        o.z = (short)__bfloat16_as_ushort(__float2bfloat16(v.z));
        o.w = (short)__bfloat16_as_ushort(__float2bfloat16(v.w));
        ((bf16x4*)out)[j] = o;
    }
}

// per-block partial sums over chunks of 1024
__global__ void scan1_kernel(const int* __restrict__ deg, int* __restrict__ bsum) {
    __shared__ int s[256];
    int t = threadIdx.x;
    int base = blockIdx.x * SCAN_CHUNK + t * 4;
    int v = 0;
    for (int k = 0; k < 4; k++) { int i = base + k; if (i < N_NODES) v += deg[i]; }
    s[t] = v;
    __syncthreads();
    for (int off = 128; off > 0; off >>= 1) { if (t < off) s[t] += s[t + off]; __syncthreads(); }
    if (t == 0) bsum[blockIdx.x] = s[0];
}

__global__ void scan2_kernel(const int* __restrict__ bsum, int* __restrict__ bscan,
                             int* __restrict__ row_start, int nb) {
    if (threadIdx.x == 0) {
        int run = 0;
        for (int b = 0; b < nb; b++) { bscan[b] = run; run += bsum[b]; }
        row_start[N_NODES] = run;
    }
}

__global__ void scan3_kernel(const int* __restrict__ deg, const int* __restrict__ bscan,
                             int* __restrict__ row_start) {
    __shared__ int s[256];
    int t = threadIdx.x;
    int base = blockIdx.x * SCAN_CHUNK + t * 4;
    int v[4]; int tot = 0;
    for (int k = 0; k < 4; k++) { int i = base + k; v[k] = (i < N_NODES) ? deg[i] : 0; tot += v[k]; }
    s[t] = tot;
    __syncthreads();
    for (int off = 1; off < 256; off <<= 1) {
        int a = (t >= off) ? s[t - off] : 0;
        __syncthreads();
        s[t] += a;
        __syncthreads();
    }
    int run = s[t] - tot + bscan[blockIdx.x];  // exclusive prefix for this thread
    for (int k = 0; k < 4; k++) {
        int i = base + k;
        if (i < N_NODES) row_start[i] = run;
        run += v[k];
    }
}

// atomic-free scatter, 4 edges per thread batched for ILP.
// Stores PRE-SCALED src row byte-offset (src*256) to save per-edge addr math in agg.
#define FI_UNROLL 4
__global__ void fill_kernel(const int* __restrict__ src, const int* __restrict__ dst,
                            const float* __restrict__ ew, const int* __restrict__ rank,
                            const int* __restrict__ row_start, int2* __restrict__ sw_s) {
    int tid = blockIdx.x * blockDim.x + threadIdx.x;
    int nthreads = gridDim.x * blockDim.x;
    int d_[FI_UNROLL], r_[FI_UNROLL], s_[FI_UNROLL], w_[FI_UNROLL], rs_[FI_UNROLL];
#pragma unroll
    for (int k = 0; k < FI_UNROLL; k++) {
        int e = tid + k * nthreads;
        if (e < N_EDGES) {
            d_[k] = dst[e]; r_[k] = rank[e]; s_[k] = src[e] << 8; w_[k] = __float_as_int(ew[e]);
        } else d_[k] = -1;
    }
#pragma unroll
    for (int k = 0; k < FI_UNROLL; k++)
        if (d_[k] >= 0) rs_[k] = row_start[d_[k]];
#pragma unroll
    for (int k = 0; k < FI_UNROLL; k++)
        if (d_[k] >= 0) sw_s[rs_[k] + r_[k]] = make_int2(s_[k], w_[k]);
}

// Fused aggregate + GEMM. Block = 4 waves owns a 16-row tile (N_NODES % 16 == 0).
// Agg: QUARTER-wave edge grouping — lane owns 8 channels (bf16x8 16B gathers);
// lane group q = lane>>4 handles edge i+q. 4 nodes interleaved -> 4 x 16B loads
// per joint-loop iter (x2 unroll = 8 in flight). Reduction: shfl_xor(16,32).
// GEMM: column-split across waves; bf16 out staged in LDS for coalesced stores.
template <int RELU, int ZERO0, int OUTBF>
__global__ __launch_bounds__(256, 4) void aggmm_kernel(const __hip_bfloat16* __restrict__ x,
                                                       const int* __restrict__ row_start,
                                                       const int2* __restrict__ sw_s,
                                                       const float* __restrict__ eps, int li,
                                                       const __hip_bfloat16* __restrict__ W,
                                                       const float* __restrict__ bias,
                                                       void* __restrict__ outv) {
    __shared__ int2 s_sw[4][4][64];           // [wave][node][slot], 8 KB
    __shared__ __hip_bfloat162 s_h[16][64];   // 4 KB tile, XOR-swizzled
    int wv = threadIdx.x >> 6;
    int lane = threadIdx.x & 63;
    int row0 = blockIdx.x * 16;
    int c16 = lane & 15;      // channel group: channels [8*c16, 8*c16+8)
    int q = lane >> 4;        // edge quarter-group
    const char* xb = (const char*)x + (c16 << 4);
    float ep = 1.0f + eps[li];

    int n0 = row0 + wv * 4;
    int beg[4], cnt[4];
#pragma unroll
    for (int j = 0; j < 4; j++) {
        beg[j] = row_start[n0 + j];
        cnt[j] = row_start[n0 + j + 1] - beg[j];
    }

    // stage all 4 first edge-chunks (masked loads, zero-pad in dead lanes)
    int2 er[4];
#pragma unroll
    for (int j = 0; j < 4; j++) {
        er[j] = make_int2(0, 0);
        if (lane < cnt[j]) er[j] = sw_s[beg[j] + lane];
    }
#pragma unroll
    for (int j = 0; j < 4; j++) s_sw[wv][j][lane] = er[j];
    asm volatile("s_waitcnt lgkmcnt(0)" ::: "memory");

    float acc[4][8] = {};
    int cmax = max(max(cnt[0], cnt[1]), max(cnt[2], cnt[3]));
    int c04 = (min(cmax, 64) + 3) & ~3;
    // joint gather loop: 4 nodes x 1 edge(per quarter) = 4 x 16B loads per iter
#pragma unroll 2
    for (int i = 0; i < c04; i += 4) {
#pragma unroll
        for (int j = 0; j < 4; j++) {
            int2 e = s_sw[wv][j][i + q];
            bf16x8 v = *(const bf16x8*)(xb + e.x);
            float w = __int_as_float(e.y);
#pragma unroll
            for (int k = 0; k < 8; k++) acc[j][k] += b2f(v[k]) * w;
        }
    }
    asm volatile("" ::: "memory");

    // rare fallback: nodes with deg > 64, serial per node
    if (cmax > 64) {
#pragma unroll 1
        for (int j = 0; j < 4; j++) {
            int nd = cnt[j];
#pragma unroll 1
            for (int base = 64; base < nd; base += 64) {
                int cc = min(64, nd - base);
                int2 er2 = make_int2(0, 0);
                if (lane < cc) er2 = sw_s[beg[j] + base + lane];
                s_sw[wv][j][lane] = er2;
                asm volatile("s_waitcnt lgkmcnt(0)" ::: "memory");
                int cc4 = (cc + 3) & ~3;
                for (int i = 0; i < cc4; i += 4) {
                    int2 e = s_sw[wv][j][i + q];
                    bf16x8 v = *(const bf16x8*)(xb + e.x);
                    float w = __int_as_float(e.y);
#pragma unroll
                    for (int k = 0; k < 8; k++) acc[j][k] += b2f(v[k]) * w;
                }
                asm volatile("" ::: "memory");
            }
        }
    }

    // finalize: reduce quarters, self term, bf16 round, swizzled LDS tile write
#pragma unroll
    for (int j = 0; j < 4; j++) {
        float a[8];
#pragma unroll
        for (int k = 0; k < 8; k++) {
            float t = acc[j][k];
            t += __shfl_xor(t, 16, 64);
            t += __shfl_xor(t, 32, 64);
            a[k] = t;
        }
        if (q == 0) {
            float dinv = cnt[j] > 0 ? 1.0f / (float)cnt[j] : 0.0f;
            bf16x8 xs = *(const bf16x8*)((const char*)x + (size_t)(n0 + j) * 256 + (c16 << 4));
            bf16x8 o;
#pragma unroll
            for (int k = 0; k < 8; k++)
                o[k] = (short)__bfloat16_as_ushort(
                    __float2bfloat16(ep * b2f(xs[k]) + a[k] * dinv));
            int jr = wv * 4 + j;
            int co = (c16 << 4) ^ ((jr & 7) << 4);
            *(bf16x8*)((char*)&s_h[jr][0] + co) = o;
        }
    }
    __syncthreads();  // tile produced by all 4 waves

    // ---- GEMM phase: each wave does cols [wv*32, wv*32+32) ----
    int lr = lane & 15;   // A/W row
    int kg = lane >> 4;   // k-subgroup (8 elements each)
    bf16x8 a[4];
#pragma unroll
    for (int k = 0; k < 4; k++) {
        int cb = (kg * 16 + k * 64) ^ ((lr & 7) << 4);
        a[k] = *(const bf16x8*)((const char*)&s_h[lr][0] + cb);
    }
    __syncthreads();  // a-frags in registers; s_h free for epilogue reuse

    f32x4 accm[2];
#pragma unroll
    for (int t = 0; t < 2; t++) {
        int jt = wv * 2 + t;
        const short* Wp = (const short*)W + (size_t)(jt * 16 + lr) * DIM + kg * 8;
        f32x4 cc = {0.f, 0.f, 0.f, 0.f};
#pragma unroll
        for (int k = 0; k < 4; k++) {
            bf16x8 b = *(const bf16x8*)(Wp + k * 32);
            cc = __builtin_amdgcn_mfma_f32_16x16x32_bf16(a[k], b, cc, 0, 0, 0);
        }
        accm[t] = cc;
    }

    int colb = lane & 15;
    int rb = (lane >> 4) * 4;
    if (OUTBF) {
        // stage out-tile in LDS (row-XOR swizzle), then 256 x 16B coalesced stores
#pragma unroll
        for (int t = 0; t < 2; t++) {
            int col = (wv * 2 + t) * 16 + colb;
            float bv = bias[col];
#pragma unroll
            for (int r = 0; r < 4; r++) {
                int row = rb + r;
                float v = accm[t][r] + bv;
                if (RELU) v = fmaxf(v, 0.f);
                if (ZERO0 && blockIdx.x == 0 && row == 0) v = 0.f;
                int bo = (row * 256 + col * 2) ^ ((row & 7) << 4);
                *(__hip_bfloat16*)((char*)s_h + bo) = __float2bfloat16(v);
            }
        }
        __syncthreads();
        int row = threadIdx.x >> 4, cc16 = threadIdx.x & 15;
        int bo = (row * 256 + cc16 * 16) ^ ((row & 7) << 4);
        bf16x8 vv = *(const bf16x8*)((const char*)s_h + bo);
        *(bf16x8*)((char*)outv + (size_t)(row0 + row) * 256 + cc16 * 16) = vv;
    } else {
#pragma unroll
        for (int t = 0; t < 2; t++) {
            int col = (wv * 2 + t) * 16 + colb;
            float bv = bias[col];
#pragma unroll
            for (int r = 0; r < 4; r++) {
                int grow = row0 + rb + r;
                float v = accm[t][r] + bv;
                if (RELU) v = fmaxf(v, 0.f);
                if (ZERO0 && grow == 0) v = 0.f;
                ((float*)outv)[(size_t)grow * DIM + col] = v;
            }
        }
    }
}

extern "C" void kernel_launch(void* const* d_in, const int* in_sizes, int n_in,
                              void* d_out, int out_size, void* d_ws, size_t ws_size,
                              hipStream_t stream) {
    const float* emb = (const float*)d_in[0];
    const float* w1  = (const float*)d_in[1];
    const float* b1  = (const float*)d_in[2];
    const float* w2  = (const float*)d_in[3];
    const float* b2  = (const float*)d_in[4];
    const float* eps = (const float*)d_in[5];
    const float* ew  = (const float*)d_in[6];
    const int* src   = (const int*)d_in[7];
    const int* dst   = (const int*)d_in[8];
    float* out = (float*)d_out;

    char* base = (char*)d_ws;
    size_t off = 0;
    auto alloc = [&](size_t bytes) -> char* {
        char* p = base + off;
        off += (bytes + 255) & ~(size_t)255;
        return p;
    };
    int* deg            = (int*)alloc((size_t)N_NODES * 4);
    int* row_start      = (int*)alloc((size_t)(N_NODES + 1) * 4);
    int* rank           = (int*)alloc((size_t)N_EDGES * 4);
    int* bsum           = (int*)alloc(128 * 4);
    int* bscan          = (int*)alloc(128 * 4);
    int2* sw_s          = (int2*)alloc((size_t)N_EDGES * 8);
    __hip_bfloat16* xb  = (__hip_bfloat16*)alloc((size_t)N_NODES * DIM * 2);
    __hip_bfloat16* xc  = (__hip_bfloat16*)alloc((size_t)N_NODES * DIM * 2);
    __hip_bfloat16* embb= (__hip_bfloat16*)alloc((size_t)N_NODES * DIM * 2);
    __hip_bfloat16* w1b = (__hip_bfloat16*)alloc(DIM * DIM * 2);
    __hip_bfloat16* w2b = (__hip_bfloat16*)alloc(DIM * DIM * 2);

    hipMemsetAsync(deg, 0, (size_t)N_NODES * 4, stream);

    // merged degrank + dtype conversions (independent work, co-scheduled)
    {
        int n4 = N_NODES * DIM / 4 + 2 * (DIM * DIM / 4);
        int cvtb = (n4 + 255) / 256;
        degcvt_kernel<<<2048 + cvtb, 256, 0, stream>>>(dst, deg, rank, emb, w1, w2,
                                                       embb, w1b, w2b);
    }

    int nb = (N_NODES + SCAN_CHUNK - 1) / SCAN_CHUNK;
    scan1_kernel<<<nb, 256, 0, stream>>>(deg, bsum);
    scan2_kernel<<<1, 64, 0, stream>>>(bsum, bscan, row_start, nb);
    scan3_kernel<<<nb, 256, 0, stream>>>(deg, bscan, row_start);
    {
        int nthreads = ((N_EDGES + FI_UNROLL - 1) / FI_UNROLL + 255) & ~255;
        fill_kernel<<<nthreads / 256, 256, 0, stream>>>(src, dst, ew, rank, row_start, sw_s);
    }

    // fused layers (ping-pong buffers: embb -> xb -> xc -> out)
    int blocks = N_NODES / 16;  // 6250, exact
    aggmm_kernel<1, 0, 1><<<blocks, 256, 0, stream>>>(embb, row_start, sw_s, eps, 0, w1b, b1, xb);
    aggmm_kernel<1, 0, 1><<<blocks, 256, 0, stream>>>(xb,   row_start, sw_s, eps, 1, w2b, b2, xc);
    aggmm_kernel<0, 1, 0><<<blocks, 256, 0, stream>>>(xc,   row_start, sw_s, eps, 2, w2b, b2, out);
}